// Round 1
// 555.357 us; speedup vs baseline: 1.0631x; 1.0631x over previous
//
#include <hip/hip_runtime.h>
#include <hip/hip_bf16.h>

// 3-layer GCN: h = A_norm * (x @ W) + b per layer, relu between.
// GEMMs on MFMA via split-bf16 (x = hi+lo, A@B ~= AhBh+AhBl+AlBh, fp32 accum).
// Aggregation via single-pass fixed-slot CSR, built XCD-range-partitioned:
// block b -> dst range (b&7); under round-robin dispatch each XCD's slot writes
// stay in its own L2 (19.2MB/8 = 2.4MB < 4MB). Degrees ~ Poisson(16); SLOTS=48
// overflow prob ~1e-10/node, agg guards with min(cnt,48).
// 128-wide messages bf16 (halves gather traffic); agg128 packs 2 nodes per wave
// (half-wave x ushort4 = 512B per gather instruction).
//
// R1: GEMMs were latency-bound (MfmaUtil 7%, VALUBusy 10%, HBM 10%, Occ 20%).
// Restructured to 64-row tiles (2x grid -> 1563 blocks, ~6/CU) with a
// register-staged double-buffered pipeline: next K-tile's global loads issue
// before the current tile's MFMAs, so HBM latency hides under compute.
// Numerics identical to the verified kernel.

#define WAVE 64
#define SLOTS 48
#define FILL_NR 8
#define FILL_NCHUNK 784

typedef short short8v __attribute__((ext_vector_type(8)));
typedef float f32x4 __attribute__((ext_vector_type(4)));

__device__ inline void split_bf16(float v, ushort& hi, ushort& lo) {
    __hip_bfloat16 h = __float2bfloat16(v);
    float hf = __bfloat162float(h);
    __hip_bfloat16 l = __float2bfloat16(v - hf);
    hi = *reinterpret_cast<ushort*>(&h);
    lo = *reinterpret_cast<ushort*>(&l);
}

__device__ inline float bf2f(ushort u) {
    unsigned int t = ((unsigned int)u) << 16;
    return __uint_as_float(t);
}

__device__ inline ushort f2bf(float v) {
    __hip_bfloat16 h = __float2bfloat16(v);
    return *reinterpret_cast<ushort*>(&h);
}

// ---------------- XCD-partitioned single-pass CSR ----------------
// block b: range r = b&7 (XCD-affine under round-robin dispatch), chunk c = b>>3.

__global__ void k_fill_part(const int* __restrict__ src, const int* __restrict__ dst,
                            int* __restrict__ cnt, int* __restrict__ slots,
                            int E, int N) {
    int b = blockIdx.x;
    int r = b & (FILL_NR - 1);
    int c = b >> 3;
    int lo = (int)((long long)E * c / FILL_NCHUNK);
    int hi = (int)((long long)E * (c + 1) / FILL_NCHUNK);
    int rlo = (int)((long long)N * r / FILL_NR);
    int rhi = (int)((long long)N * (r + 1) / FILL_NR);
    for (int e = lo + threadIdx.x; e < hi; e += 256) {
        int d = dst[e];
        if (d >= rlo && d < rhi) {
            int p = atomicAdd(&cnt[d], 1);
            if (p < SLOTS) slots[(size_t)d * SLOTS + p] = src[e];
        }
    }
}

__global__ void k_dinv(const int* __restrict__ cnt, float* __restrict__ dinv, int N) {
    int i = blockIdx.x * blockDim.x + threadIdx.x;
    if (i < N) dinv[i] = rsqrtf((float)cnt[i] + 1.0f);
}

// ---------------- W pre-split: W[K][M] fp32 -> Wt_hi/lo[Mpad][K] bf16 (transposed) ----------------

__global__ void k_wsplit(const float* __restrict__ W, ushort* __restrict__ Wth,
                         ushort* __restrict__ Wtl, int K, int M, int Mpad) {
    int idx = blockIdx.x * 256 + threadIdx.x;
    if (idx >= K * Mpad) return;
    int k = idx / Mpad, m = idx % Mpad;
    float v = (m < M) ? W[(size_t)k * M + m] : 0.f;
    ushort h, l;
    split_bf16(v, h, l);
    Wth[(size_t)m * K + k] = h;
    Wtl[(size_t)m * K + k] = l;
}

// ---------------- MFMA GEMM, 128 cols, 64-row tile, reg-staged pipeline ----------------
// 4 waves: wave&1 -> row half (32), wave>>1 -> col half (64). acc[2][4].
// Per K-step (32): prefetch next tile's A(fp32)+B(bf16) to regs before MFMAs.

template <int K, bool BF16OUT>
__global__ __launch_bounds__(256) void gemm_mfma128(const float* __restrict__ A,
                                                    const ushort* __restrict__ Wth,
                                                    const ushort* __restrict__ Wtl,
                                                    const float* __restrict__ rowscale,
                                                    void* __restrict__ outv, int N) {
    constexpr int LD = 40;
    __shared__ ushort Ah[64 * LD], Al[64 * LD], Bh[128 * LD], Bl[128 * LD];

    const int tid = threadIdx.x;
    const int lane = tid & 63, wave = tid >> 6;
    const int wr = (wave & 1) * 32, wc = (wave >> 1) * 64;
    const int r0 = blockIdx.x * 64;
    const int tr = lane & 15, quad = lane >> 4;

    // staging coords: A rows (tid>>3, +32) @ k-offset (tid&7)*4; B cols (tid>>2, +64) @ part (tid&3)*8
    const int arow = tid >> 3;
    const int akq = (tid & 7) * 4;
    const int bcol = tid >> 2;
    const int bpart = (tid & 3) * 8;
    int ga0 = r0 + arow;      if (ga0 > N - 1) ga0 = N - 1;
    int ga1 = r0 + arow + 32; if (ga1 > N - 1) ga1 = N - 1;
    const float* Ap0 = A + (size_t)ga0 * K + akq;
    const float* Ap1 = A + (size_t)ga1 * K + akq;
    const ushort* Wh0 = Wth + (size_t)bcol * K + bpart;
    const ushort* Wl0 = Wtl + (size_t)bcol * K + bpart;
    const ushort* Wh1 = Wth + (size_t)(bcol + 64) * K + bpart;
    const ushort* Wl1 = Wtl + (size_t)(bcol + 64) * K + bpart;

    f32x4 acc[2][4];
#pragma unroll
    for (int i = 0; i < 2; ++i)
#pragma unroll
        for (int j = 0; j < 4; ++j) acc[i][j] = (f32x4)(0.f);

    float4 a0r0, a0r1, a1r0, a1r1;
    uint4 b0h0, b0l0, b0h1, b0l1, b1h0, b1l0, b1h1, b1l1;

    auto loadA = [&](float4& x0, float4& x1, int kc) {
        x0 = *reinterpret_cast<const float4*>(Ap0 + kc);
        x1 = *reinterpret_cast<const float4*>(Ap1 + kc);
    };
    auto loadB = [&](uint4& h0, uint4& l0, uint4& h1, uint4& l1, int kc) {
        h0 = *reinterpret_cast<const uint4*>(Wh0 + kc);
        l0 = *reinterpret_cast<const uint4*>(Wl0 + kc);
        h1 = *reinterpret_cast<const uint4*>(Wh1 + kc);
        l1 = *reinterpret_cast<const uint4*>(Wl1 + kc);
    };
    auto writeAB = [&](const float4& x0, const float4& x1, const uint4& h0, const uint4& l0,
                       const uint4& h1, const uint4& l1) {
        ushort ha, la, hb, lb, hc, lc, hd, ld_;
        split_bf16(x0.x, ha, la);
        split_bf16(x0.y, hb, lb);
        split_bf16(x0.z, hc, lc);
        split_bf16(x0.w, hd, ld_);
        *reinterpret_cast<ushort4*>(&Ah[arow * LD + akq]) = make_ushort4(ha, hb, hc, hd);
        *reinterpret_cast<ushort4*>(&Al[arow * LD + akq]) = make_ushort4(la, lb, lc, ld_);
        split_bf16(x1.x, ha, la);
        split_bf16(x1.y, hb, lb);
        split_bf16(x1.z, hc, lc);
        split_bf16(x1.w, hd, ld_);
        *reinterpret_cast<ushort4*>(&Ah[(arow + 32) * LD + akq]) = make_ushort4(ha, hb, hc, hd);
        *reinterpret_cast<ushort4*>(&Al[(arow + 32) * LD + akq]) = make_ushort4(la, lb, lc, ld_);
        *reinterpret_cast<uint4*>(&Bh[bcol * LD + bpart]) = h0;
        *reinterpret_cast<uint4*>(&Bl[bcol * LD + bpart]) = l0;
        *reinterpret_cast<uint4*>(&Bh[(bcol + 64) * LD + bpart]) = h1;
        *reinterpret_cast<uint4*>(&Bl[(bcol + 64) * LD + bpart]) = l1;
    };
    auto compute = [&]() {
        short8v ah[2], al[2], bhv[4], blv[4];
#pragma unroll
        for (int i = 0; i < 2; ++i) {
            ah[i] = *reinterpret_cast<const short8v*>(&Ah[(wr + i * 16 + tr) * LD + quad * 8]);
            al[i] = *reinterpret_cast<const short8v*>(&Al[(wr + i * 16 + tr) * LD + quad * 8]);
        }
#pragma unroll
        for (int j = 0; j < 4; ++j) {
            bhv[j] = *reinterpret_cast<const short8v*>(&Bh[(wc + j * 16 + tr) * LD + quad * 8]);
            blv[j] = *reinterpret_cast<const short8v*>(&Bl[(wc + j * 16 + tr) * LD + quad * 8]);
        }
#pragma unroll
        for (int i = 0; i < 2; ++i)
#pragma unroll
            for (int j = 0; j < 4; ++j) {
                acc[i][j] = __builtin_amdgcn_mfma_f32_16x16x32_bf16(ah[i], bhv[j], acc[i][j], 0, 0, 0);
                acc[i][j] = __builtin_amdgcn_mfma_f32_16x16x32_bf16(ah[i], blv[j], acc[i][j], 0, 0, 0);
                acc[i][j] = __builtin_amdgcn_mfma_f32_16x16x32_bf16(al[i], bhv[j], acc[i][j], 0, 0, 0);
            }
    };

    loadA(a0r0, a0r1, 0);
    loadB(b0h0, b0l0, b0h1, b0l1, 0);
    for (int kc = 0; kc < K; kc += 64) {
        writeAB(a0r0, a0r1, b0h0, b0l0, b0h1, b0l1);
        __syncthreads();
        loadA(a1r0, a1r1, kc + 32);                 // prefetch k-step kc+32
        loadB(b1h0, b1l0, b1h1, b1l1, kc + 32);
        compute();                                  // compute kc (loads in flight)
        __syncthreads();
        writeAB(a1r0, a1r1, b1h0, b1l0, b1h1, b1l1);
        __syncthreads();
        if (kc + 64 < K) {
            loadA(a0r0, a0r1, kc + 64);             // prefetch k-step kc+64
            loadB(b0h0, b0l0, b0h1, b0l1, kc + 64);
        }
        compute();                                  // compute kc+32
        __syncthreads();
    }

#pragma unroll
    for (int i = 0; i < 2; ++i) {
        int rbase = r0 + wr + i * 16 + quad * 4;
        float rs[4];
#pragma unroll
        for (int reg = 0; reg < 4; ++reg) {
            int r = rbase + reg;
            rs[reg] = (r < N) ? rowscale[r] : 0.f;
        }
#pragma unroll
        for (int j = 0; j < 4; ++j) {
            int c = wc + j * 16 + tr;
#pragma unroll
            for (int reg = 0; reg < 4; ++reg) {
                int r = rbase + reg;
                if (r < N) {
                    float v = acc[i][j][reg] * rs[reg];
                    if (BF16OUT)
                        ((ushort*)outv)[(size_t)r * 128 + c] = f2bf(v);
                    else
                        ((float*)outv)[(size_t)r * 128 + c] = v;
                }
            }
        }
    }
}

// ---------------- MFMA GEMM, 40 cols (padded to 48), K=128, 64-row tile ----------------
// 4 waves x 16 rows each, all 48 cols. acc[3]. Same reg-staged pipeline.

__global__ __launch_bounds__(256) void gemm_mfma40(const float* __restrict__ A,
                                                   const ushort* __restrict__ Wth,
                                                   const ushort* __restrict__ Wtl,
                                                   const float* __restrict__ rowscale,
                                                   float* __restrict__ out, int N) {
    constexpr int K = 128, LD = 40, M = 40;
    __shared__ ushort Ah[64 * LD], Al[64 * LD], Bh[48 * LD], Bl[48 * LD];

    const int tid = threadIdx.x;
    const int lane = tid & 63, wave = tid >> 6;
    const int wr = wave * 16;
    const int r0 = blockIdx.x * 64;
    const int tr = lane & 15, quad = lane >> 4;

    const int arow = tid >> 3;
    const int akq = (tid & 7) * 4;
    const bool bact = tid < 192;
    const int bcol = tid >> 2;
    const int bpart = (tid & 3) * 8;
    int ga0 = r0 + arow;      if (ga0 > N - 1) ga0 = N - 1;
    int ga1 = r0 + arow + 32; if (ga1 > N - 1) ga1 = N - 1;
    const float* Ap0 = A + (size_t)ga0 * K + akq;
    const float* Ap1 = A + (size_t)ga1 * K + akq;
    const ushort* Wh0 = Wth + (size_t)bcol * K + bpart;
    const ushort* Wl0 = Wtl + (size_t)bcol * K + bpart;

    f32x4 acc[3];
#pragma unroll
    for (int j = 0; j < 3; ++j) acc[j] = (f32x4)(0.f);

    float4 a0r0, a0r1, a1r0, a1r1;
    uint4 b0h, b0l, b1h, b1l;

    auto loadA = [&](float4& x0, float4& x1, int kc) {
        x0 = *reinterpret_cast<const float4*>(Ap0 + kc);
        x1 = *reinterpret_cast<const float4*>(Ap1 + kc);
    };
    auto loadB = [&](uint4& h, uint4& l, int kc) {
        if (bact) {
            h = *reinterpret_cast<const uint4*>(Wh0 + kc);
            l = *reinterpret_cast<const uint4*>(Wl0 + kc);
        }
    };
    auto writeAB = [&](const float4& x0, const float4& x1, const uint4& h, const uint4& l) {
        ushort ha, la, hb, lb, hc, lc, hd, ld_;
        split_bf16(x0.x, ha, la);
        split_bf16(x0.y, hb, lb);
        split_bf16(x0.z, hc, lc);
        split_bf16(x0.w, hd, ld_);
        *reinterpret_cast<ushort4*>(&Ah[arow * LD + akq]) = make_ushort4(ha, hb, hc, hd);
        *reinterpret_cast<ushort4*>(&Al[arow * LD + akq]) = make_ushort4(la, lb, lc, ld_);
        split_bf16(x1.x, ha, la);
        split_bf16(x1.y, hb, lb);
        split_bf16(x1.z, hc, lc);
        split_bf16(x1.w, hd, ld_);
        *reinterpret_cast<ushort4*>(&Ah[(arow + 32) * LD + akq]) = make_ushort4(ha, hb, hc, hd);
        *reinterpret_cast<ushort4*>(&Al[(arow + 32) * LD + akq]) = make_ushort4(la, lb, lc, ld_);
        if (bact) {
            *reinterpret_cast<uint4*>(&Bh[bcol * LD + bpart]) = h;
            *reinterpret_cast<uint4*>(&Bl[bcol * LD + bpart]) = l;
        }
    };
    auto compute = [&]() {
        short8v ah, al, bhv[3], blv[3];
        ah = *reinterpret_cast<const short8v*>(&Ah[(wr + tr) * LD + quad * 8]);
        al = *reinterpret_cast<const short8v*>(&Al[(wr + tr) * LD + quad * 8]);
#pragma unroll
        for (int j = 0; j < 3; ++j) {
            bhv[j] = *reinterpret_cast<const short8v*>(&Bh[(j * 16 + tr) * LD + quad * 8]);
            blv[j] = *reinterpret_cast<const short8v*>(&Bl[(j * 16 + tr) * LD + quad * 8]);
        }
#pragma unroll
        for (int j = 0; j < 3; ++j) {
            acc[j] = __builtin_amdgcn_mfma_f32_16x16x32_bf16(ah, bhv[j], acc[j], 0, 0, 0);
            acc[j] = __builtin_amdgcn_mfma_f32_16x16x32_bf16(ah, blv[j], acc[j], 0, 0, 0);
            acc[j] = __builtin_amdgcn_mfma_f32_16x16x32_bf16(al, bhv[j], acc[j], 0, 0, 0);
        }
    };

    loadA(a0r0, a0r1, 0);
    loadB(b0h, b0l, 0);
    for (int kc = 0; kc < K; kc += 64) {
        writeAB(a0r0, a0r1, b0h, b0l);
        __syncthreads();
        loadA(a1r0, a1r1, kc + 32);
        loadB(b1h, b1l, kc + 32);
        compute();
        __syncthreads();
        writeAB(a1r0, a1r1, b1h, b1l);
        __syncthreads();
        if (kc + 64 < K) {
            loadA(a0r0, a0r1, kc + 64);
            loadB(b0h, b0l, kc + 64);
        }
        compute();
        __syncthreads();
    }

    {
        int rbase = r0 + wr + quad * 4;
        float rs[4];
#pragma unroll
        for (int reg = 0; reg < 4; ++reg) {
            int r = rbase + reg;
            rs[reg] = (r < N) ? rowscale[r] : 0.f;
        }
#pragma unroll
        for (int j = 0; j < 3; ++j) {
            int c = j * 16 + tr;
#pragma unroll
            for (int reg = 0; reg < 4; ++reg) {
                int r = rbase + reg;
                if (r < N && c < M) out[(size_t)r * M + c] = acc[j][reg] * rs[reg];
            }
        }
    }
}

// ---------------- aggregation, 128-wide bf16: 2 nodes per wave ----------------
// half-wave (32 lanes) per node, ushort4/lane: one gather inst = 512B (2 rows).
// Lanes past a node's count gather the node's own (L1-warm) row, masked add.

template <bool RELU>
__global__ __launch_bounds__(256) void agg128_bf2(const ushort* __restrict__ S,
                                                  const int* __restrict__ slots,
                                                  const int* __restrict__ cnt,
                                                  const float* __restrict__ dinv,
                                                  const float* __restrict__ bias,
                                                  float* __restrict__ out, int N) {
    int w = (blockIdx.x * blockDim.x + threadIdx.x) >> 6;
    int lane = threadIdx.x & 63;
    int npair = (N + 1) >> 1;
    if (w >= npair) return;
    int half = lane >> 5, sub = lane & 31;
    int node = 2 * w + half;
    bool valid = node < N;
    int snode = valid ? node : 0;
    const ushort4* S4 = (const ushort4*)S;  // row = 32 x ushort4
    const int* row = slots + (size_t)snode * SLOTS;
    int c = valid ? cnt[snode] : 0;
    if (c > SLOTS) c = SLOTS;
    int cmax = max(c, __shfl(c, lane ^ 32));

    ushort4 sv = S4[(size_t)snode * 32 + sub];  // self loop
    float a0 = bf2f(sv.x), a1 = bf2f(sv.y), a2 = bf2f(sv.z), a3 = bf2f(sv.w);

    int e = 0;
    for (; e + 8 <= cmax; e += 8) {
        int s[8];
#pragma unroll
        for (int u = 0; u < 8; ++u) s[u] = (e + u < c) ? row[e + u] : snode;
        ushort4 v[8];
#pragma unroll
        for (int u = 0; u < 8; ++u) v[u] = S4[(size_t)s[u] * 32 + sub];
#pragma unroll
        for (int u = 0; u < 8; ++u) {
            float m = (e + u < c) ? 1.f : 0.f;
            a0 += m * bf2f(v[u].x);
            a1 += m * bf2f(v[u].y);
            a2 += m * bf2f(v[u].z);
            a3 += m * bf2f(v[u].w);
        }
    }
    for (; e < cmax; ++e) {
        int s = (e < c) ? row[e] : snode;
        ushort4 v = S4[(size_t)s * 32 + sub];
        float m = (e < c) ? 1.f : 0.f;
        a0 += m * bf2f(v.x);
        a1 += m * bf2f(v.y);
        a2 += m * bf2f(v.z);
        a3 += m * bf2f(v.w);
    }

    if (valid) {
        float di = dinv[node];
        float4 bv = ((const float4*)bias)[sub];
        float o0 = a0 * di + bv.x;
        float o1 = a1 * di + bv.y;
        float o2 = a2 * di + bv.z;
        float o3 = a3 * di + bv.w;
        if (RELU) {
            o0 = fmaxf(o0, 0.f);
            o1 = fmaxf(o1, 0.f);
            o2 = fmaxf(o2, 0.f);
            o3 = fmaxf(o3, 0.f);
        }
        ((float4*)out)[(size_t)node * 32 + sub] = make_float4(o0, o1, o2, o3);
    }
}

// fp32 messages, M=40 (final layer), wave per node
__global__ __launch_bounds__(256) void agg40(const float* __restrict__ S,
                                             const int* __restrict__ slots,
                                             const int* __restrict__ cnt,
                                             const float* __restrict__ dinv,
                                             const float* __restrict__ bias,
                                             float* __restrict__ out, int N) {
    int wid = (blockIdx.x * blockDim.x + threadIdx.x) >> 6;
    int lane = threadIdx.x & 63;
    if (wid >= N || lane >= 40) return;
    const int* row = slots + (size_t)wid * SLOTS;
    int c = cnt[wid];
    if (c > SLOTS) c = SLOTS;
    float acc = S[(size_t)wid * 40 + lane];
    int e = 0;
    for (; e + 8 <= c; e += 8) {
        int s[8];
#pragma unroll
        for (int u = 0; u < 8; ++u) s[u] = row[e + u];
        float v[8];
#pragma unroll
        for (int u = 0; u < 8; ++u) v[u] = S[(size_t)s[u] * 40 + lane];
#pragma unroll
        for (int u = 0; u < 8; ++u) acc += v[u];
    }
    for (; e < c; ++e) acc += S[(size_t)row[e] * 40 + lane];
    out[(size_t)wid * 40 + lane] = acc * dinv[wid] + bias[lane];
}

// ---------------- launch ----------------

extern "C" void kernel_launch(void* const* d_in, const int* in_sizes, int n_in,
                              void* d_out, int out_size, void* d_ws, size_t ws_size,
                              hipStream_t stream) {
    const float* x  = (const float*)d_in[0];
    const int*   ei = (const int*)d_in[1];
    const float* W1 = (const float*)d_in[2];
    const float* b1 = (const float*)d_in[3];
    const float* W2 = (const float*)d_in[4];
    const float* b2 = (const float*)d_in[5];
    const float* W3 = (const float*)d_in[6];
    const float* b3 = (const float*)d_in[7];
    float* out = (float*)d_out;

    const int IN_DIM = 256, HID = 128;
    const int N = in_sizes[0] / IN_DIM;
    const int E = in_sizes[1] / 2;
    const int* srcE = ei;
    const int* dstE = ei + E;

    char* ws = (char*)d_ws;
    size_t off = 0;
    auto alloc = [&](size_t bytes) -> void* {
        off = (off + 255) & ~(size_t)255;
        void* p = ws + off;
        off += bytes;
        return p;
    };
    int*    cnt   = (int*)alloc((size_t)N * 4);
    float*  dinv  = (float*)alloc((size_t)N * 4);
    int*    slots = (int*)alloc((size_t)N * SLOTS * 4);     // 19.2 MB
    ushort* bufS  = (ushort*)alloc((size_t)N * HID * 4);    // bf16 msgs (128) or fp32 msgs (40)
    float*  bufH  = (float*)alloc((size_t)N * HID * 4);     // fp32 h
    ushort* W1th  = (ushort*)alloc((size_t)128 * 256 * 2);
    ushort* W1tl  = (ushort*)alloc((size_t)128 * 256 * 2);
    ushort* W2th  = (ushort*)alloc((size_t)128 * 128 * 2);
    ushort* W2tl  = (ushort*)alloc((size_t)128 * 128 * 2);
    ushort* W3th  = (ushort*)alloc((size_t)48 * 128 * 2);
    ushort* W3tl  = (ushort*)alloc((size_t)48 * 128 * 2);

    const int NB = (N + 255) / 256;
    const int AGGB = (N * WAVE + 255) / 256;
    const int AGG2B = (((N + 1) / 2) * WAVE + 255) / 256;
    const int GB64 = (N + 63) / 64;
    const int FB = FILL_NR * FILL_NCHUNK;

    // W pre-split (tiny)
    k_wsplit<<<(256 * 128 + 255) / 256, 256, 0, stream>>>(W1, W1th, W1tl, 256, 128, 128);
    k_wsplit<<<(128 * 128 + 255) / 256, 256, 0, stream>>>(W2, W2th, W2tl, 128, 128, 128);
    k_wsplit<<<(128 * 48 + 255) / 256, 256, 0, stream>>>(W3, W3th, W3tl, 128, 40, 48);

    // single-pass XCD-partitioned CSR + dinv
    hipMemsetAsync(cnt, 0, (size_t)N * 4, stream);
    k_fill_part<<<FB, 256, 0, stream>>>(srcE, dstE, cnt, slots, E, N);
    k_dinv<<<NB, 256, 0, stream>>>(cnt, dinv, N);

    // Layer 1: 256 -> 128, relu (bf16 messages)
    gemm_mfma128<256, true><<<GB64, 256, 0, stream>>>(x, W1th, W1tl, dinv, bufS, N);
    agg128_bf2<true><<<AGG2B, 256, 0, stream>>>(bufS, slots, cnt, dinv, b1, bufH, N);
    // Layer 2: 128 -> 128, relu (bf16 messages)
    gemm_mfma128<128, true><<<GB64, 256, 0, stream>>>(bufH, W2th, W2tl, dinv, bufS, N);
    agg128_bf2<true><<<AGG2B, 256, 0, stream>>>(bufS, slots, cnt, dinv, b2, bufH, N);
    // Layer 3: 128 -> 40, no relu (fp32 messages)
    gemm_mfma40<<<GB64, 256, 0, stream>>>(bufH, W3th, W3tl, dinv, (float*)bufS, N);
    agg40<<<AGGB, 256, 0, stream>>>((float*)bufS, slots, cnt, dinv, b3, out, N);
}

// Round 2
// 550.213 us; speedup vs baseline: 1.0730x; 1.0093x over previous
//
#include <hip/hip_runtime.h>
#include <hip/hip_bf16.h>

// 3-layer GCN: h = A_norm * (x @ W) + b per layer, relu between.
// GEMMs on MFMA via split-bf16 (x = hi+lo, A@B ~= AhBh+AhBl+AlBh, fp32 accum).
// Aggregation via single-pass fixed-slot CSR, built XCD-range-partitioned:
// block b -> dst range (b&7); under round-robin dispatch each XCD's slot writes
// stay in its own L2 (19.2MB/8 = 2.4MB < 4MB). Degrees ~ Poisson(16); SLOTS=48
// overflow prob ~1e-10/node, agg guards with min(cnt,48).
// 128-wide messages bf16 (halves gather traffic); agg128 packs 2 nodes per wave
// (half-wave x ushort4 = 512B per gather instruction).
//
// R1: GEMMs were latency-bound (MfmaUtil 7%, VALUBusy 10%, HBM 10%, Occ 20%).
// Restructured to 64-row tiles (2x grid -> 1563 blocks, ~6/CU) with a
// register-staged double-buffered pipeline. Worked: GEMMs dropped out of top-5.
// R2: k_fill_part now #1 (91us). WRITE_SIZE 78.6MB vs 19.6MB useful = 4x write
// amplification: the streaming dst/src reads (7.2MB/XCD) evict the hot slot
// lines from each XCD's 4MB L2 between a node's ~16 scattered writes. Fix:
// nontemporal loads for the edge stream so the slot working set stays resident.

#define WAVE 64
#define SLOTS 48
#define FILL_NR 8
#define FILL_NCHUNK 784

typedef short short8v __attribute__((ext_vector_type(8)));
typedef float f32x4 __attribute__((ext_vector_type(4)));

__device__ inline void split_bf16(float v, ushort& hi, ushort& lo) {
    __hip_bfloat16 h = __float2bfloat16(v);
    float hf = __bfloat162float(h);
    __hip_bfloat16 l = __float2bfloat16(v - hf);
    hi = *reinterpret_cast<ushort*>(&h);
    lo = *reinterpret_cast<ushort*>(&l);
}

__device__ inline float bf2f(ushort u) {
    unsigned int t = ((unsigned int)u) << 16;
    return __uint_as_float(t);
}

__device__ inline ushort f2bf(float v) {
    __hip_bfloat16 h = __float2bfloat16(v);
    return *reinterpret_cast<ushort*>(&h);
}

// ---------------- XCD-partitioned single-pass CSR ----------------
// block b: range r = b&7 (XCD-affine under round-robin dispatch), chunk c = b>>3.
// Edge stream is nontemporal: keeps each XCD's 2.45MB cnt+slots set in its L2.

__global__ void k_fill_part(const int* __restrict__ src, const int* __restrict__ dst,
                            int* __restrict__ cnt, int* __restrict__ slots,
                            int E, int N) {
    int b = blockIdx.x;
    int r = b & (FILL_NR - 1);
    int c = b >> 3;
    int lo = (int)((long long)E * c / FILL_NCHUNK);
    int hi = (int)((long long)E * (c + 1) / FILL_NCHUNK);
    int rlo = (int)((long long)N * r / FILL_NR);
    int rhi = (int)((long long)N * (r + 1) / FILL_NR);
    for (int e = lo + threadIdx.x; e < hi; e += 256) {
        int d = __builtin_nontemporal_load(&dst[e]);
        if (d >= rlo && d < rhi) {
            int s = __builtin_nontemporal_load(&src[e]);
            int p = atomicAdd(&cnt[d], 1);
            if (p < SLOTS) slots[(size_t)d * SLOTS + p] = s;
        }
    }
}

__global__ void k_dinv(const int* __restrict__ cnt, float* __restrict__ dinv, int N) {
    int i = blockIdx.x * blockDim.x + threadIdx.x;
    if (i < N) dinv[i] = rsqrtf((float)cnt[i] + 1.0f);
}

// ---------------- W pre-split: W[K][M] fp32 -> Wt_hi/lo[Mpad][K] bf16 (transposed) ----------------

__global__ void k_wsplit(const float* __restrict__ W, ushort* __restrict__ Wth,
                         ushort* __restrict__ Wtl, int K, int M, int Mpad) {
    int idx = blockIdx.x * 256 + threadIdx.x;
    if (idx >= K * Mpad) return;
    int k = idx / Mpad, m = idx % Mpad;
    float v = (m < M) ? W[(size_t)k * M + m] : 0.f;
    ushort h, l;
    split_bf16(v, h, l);
    Wth[(size_t)m * K + k] = h;
    Wtl[(size_t)m * K + k] = l;
}

// ---------------- MFMA GEMM, 128 cols, 64-row tile, reg-staged pipeline ----------------
// 4 waves: wave&1 -> row half (32), wave>>1 -> col half (64). acc[2][4].
// Per K-step (32): prefetch next tile's A(fp32)+B(bf16) to regs before MFMAs.

template <int K, bool BF16OUT>
__global__ __launch_bounds__(256) void gemm_mfma128(const float* __restrict__ A,
                                                    const ushort* __restrict__ Wth,
                                                    const ushort* __restrict__ Wtl,
                                                    const float* __restrict__ rowscale,
                                                    void* __restrict__ outv, int N) {
    constexpr int LD = 40;
    __shared__ ushort Ah[64 * LD], Al[64 * LD], Bh[128 * LD], Bl[128 * LD];

    const int tid = threadIdx.x;
    const int lane = tid & 63, wave = tid >> 6;
    const int wr = (wave & 1) * 32, wc = (wave >> 1) * 64;
    const int r0 = blockIdx.x * 64;
    const int tr = lane & 15, quad = lane >> 4;

    // staging coords: A rows (tid>>3, +32) @ k-offset (tid&7)*4; B cols (tid>>2, +64) @ part (tid&3)*8
    const int arow = tid >> 3;
    const int akq = (tid & 7) * 4;
    const int bcol = tid >> 2;
    const int bpart = (tid & 3) * 8;
    int ga0 = r0 + arow;      if (ga0 > N - 1) ga0 = N - 1;
    int ga1 = r0 + arow + 32; if (ga1 > N - 1) ga1 = N - 1;
    const float* Ap0 = A + (size_t)ga0 * K + akq;
    const float* Ap1 = A + (size_t)ga1 * K + akq;
    const ushort* Wh0 = Wth + (size_t)bcol * K + bpart;
    const ushort* Wl0 = Wtl + (size_t)bcol * K + bpart;
    const ushort* Wh1 = Wth + (size_t)(bcol + 64) * K + bpart;
    const ushort* Wl1 = Wtl + (size_t)(bcol + 64) * K + bpart;

    f32x4 acc[2][4];
#pragma unroll
    for (int i = 0; i < 2; ++i)
#pragma unroll
        for (int j = 0; j < 4; ++j) acc[i][j] = (f32x4)(0.f);

    float4 a0r0, a0r1, a1r0, a1r1;
    uint4 b0h0, b0l0, b0h1, b0l1, b1h0, b1l0, b1h1, b1l1;

    auto loadA = [&](float4& x0, float4& x1, int kc) {
        x0 = *reinterpret_cast<const float4*>(Ap0 + kc);
        x1 = *reinterpret_cast<const float4*>(Ap1 + kc);
    };
    auto loadB = [&](uint4& h0, uint4& l0, uint4& h1, uint4& l1, int kc) {
        h0 = *reinterpret_cast<const uint4*>(Wh0 + kc);
        l0 = *reinterpret_cast<const uint4*>(Wl0 + kc);
        h1 = *reinterpret_cast<const uint4*>(Wh1 + kc);
        l1 = *reinterpret_cast<const uint4*>(Wl1 + kc);
    };
    auto writeAB = [&](const float4& x0, const float4& x1, const uint4& h0, const uint4& l0,
                       const uint4& h1, const uint4& l1) {
        ushort ha, la, hb, lb, hc, lc, hd, ld_;
        split_bf16(x0.x, ha, la);
        split_bf16(x0.y, hb, lb);
        split_bf16(x0.z, hc, lc);
        split_bf16(x0.w, hd, ld_);
        *reinterpret_cast<ushort4*>(&Ah[arow * LD + akq]) = make_ushort4(ha, hb, hc, hd);
        *reinterpret_cast<ushort4*>(&Al[arow * LD + akq]) = make_ushort4(la, lb, lc, ld_);
        split_bf16(x1.x, ha, la);
        split_bf16(x1.y, hb, lb);
        split_bf16(x1.z, hc, lc);
        split_bf16(x1.w, hd, ld_);
        *reinterpret_cast<ushort4*>(&Ah[(arow + 32) * LD + akq]) = make_ushort4(ha, hb, hc, hd);
        *reinterpret_cast<ushort4*>(&Al[(arow + 32) * LD + akq]) = make_ushort4(la, lb, lc, ld_);
        *reinterpret_cast<uint4*>(&Bh[bcol * LD + bpart]) = h0;
        *reinterpret_cast<uint4*>(&Bl[bcol * LD + bpart]) = l0;
        *reinterpret_cast<uint4*>(&Bh[(bcol + 64) * LD + bpart]) = h1;
        *reinterpret_cast<uint4*>(&Bl[(bcol + 64) * LD + bpart]) = l1;
    };
    auto compute = [&]() {
        short8v ah[2], al[2], bhv[4], blv[4];
#pragma unroll
        for (int i = 0; i < 2; ++i) {
            ah[i] = *reinterpret_cast<const short8v*>(&Ah[(wr + i * 16 + tr) * LD + quad * 8]);
            al[i] = *reinterpret_cast<const short8v*>(&Al[(wr + i * 16 + tr) * LD + quad * 8]);
        }
#pragma unroll
        for (int j = 0; j < 4; ++j) {
            bhv[j] = *reinterpret_cast<const short8v*>(&Bh[(wc + j * 16 + tr) * LD + quad * 8]);
            blv[j] = *reinterpret_cast<const short8v*>(&Bl[(wc + j * 16 + tr) * LD + quad * 8]);
        }
#pragma unroll
        for (int i = 0; i < 2; ++i)
#pragma unroll
            for (int j = 0; j < 4; ++j) {
                acc[i][j] = __builtin_amdgcn_mfma_f32_16x16x32_bf16(ah[i], bhv[j], acc[i][j], 0, 0, 0);
                acc[i][j] = __builtin_amdgcn_mfma_f32_16x16x32_bf16(ah[i], blv[j], acc[i][j], 0, 0, 0);
                acc[i][j] = __builtin_amdgcn_mfma_f32_16x16x32_bf16(al[i], bhv[j], acc[i][j], 0, 0, 0);
            }
    };

    loadA(a0r0, a0r1, 0);
    loadB(b0h0, b0l0, b0h1, b0l1, 0);
    for (int kc = 0; kc < K; kc += 64) {
        writeAB(a0r0, a0r1, b0h0, b0l0, b0h1, b0l1);
        __syncthreads();
        loadA(a1r0, a1r1, kc + 32);                 // prefetch k-step kc+32
        loadB(b1h0, b1l0, b1h1, b1l1, kc + 32);
        compute();                                  // compute kc (loads in flight)
        __syncthreads();
        writeAB(a1r0, a1r1, b1h0, b1l0, b1h1, b1l1);
        __syncthreads();
        if (kc + 64 < K) {
            loadA(a0r0, a0r1, kc + 64);             // prefetch k-step kc+64
            loadB(b0h0, b0l0, b0h1, b0l1, kc + 64);
        }
        compute();                                  // compute kc+32
        __syncthreads();
    }

#pragma unroll
    for (int i = 0; i < 2; ++i) {
        int rbase = r0 + wr + i * 16 + quad * 4;
        float rs[4];
#pragma unroll
        for (int reg = 0; reg < 4; ++reg) {
            int r = rbase + reg;
            rs[reg] = (r < N) ? rowscale[r] : 0.f;
        }
#pragma unroll
        for (int j = 0; j < 4; ++j) {
            int c = wc + j * 16 + tr;
#pragma unroll
            for (int reg = 0; reg < 4; ++reg) {
                int r = rbase + reg;
                if (r < N) {
                    float v = acc[i][j][reg] * rs[reg];
                    if (BF16OUT)
                        ((ushort*)outv)[(size_t)r * 128 + c] = f2bf(v);
                    else
                        ((float*)outv)[(size_t)r * 128 + c] = v;
                }
            }
        }
    }
}

// ---------------- MFMA GEMM, 40 cols (padded to 48), K=128, 64-row tile ----------------
// 4 waves x 16 rows each, all 48 cols. acc[3]. Same reg-staged pipeline.

__global__ __launch_bounds__(256) void gemm_mfma40(const float* __restrict__ A,
                                                   const ushort* __restrict__ Wth,
                                                   const ushort* __restrict__ Wtl,
                                                   const float* __restrict__ rowscale,
                                                   float* __restrict__ out, int N) {
    constexpr int K = 128, LD = 40, M = 40;
    __shared__ ushort Ah[64 * LD], Al[64 * LD], Bh[48 * LD], Bl[48 * LD];

    const int tid = threadIdx.x;
    const int lane = tid & 63, wave = tid >> 6;
    const int wr = wave * 16;
    const int r0 = blockIdx.x * 64;
    const int tr = lane & 15, quad = lane >> 4;

    const int arow = tid >> 3;
    const int akq = (tid & 7) * 4;
    const bool bact = tid < 192;
    const int bcol = tid >> 2;
    const int bpart = (tid & 3) * 8;
    int ga0 = r0 + arow;      if (ga0 > N - 1) ga0 = N - 1;
    int ga1 = r0 + arow + 32; if (ga1 > N - 1) ga1 = N - 1;
    const float* Ap0 = A + (size_t)ga0 * K + akq;
    const float* Ap1 = A + (size_t)ga1 * K + akq;
    const ushort* Wh0 = Wth + (size_t)bcol * K + bpart;
    const ushort* Wl0 = Wtl + (size_t)bcol * K + bpart;

    f32x4 acc[3];
#pragma unroll
    for (int j = 0; j < 3; ++j) acc[j] = (f32x4)(0.f);

    float4 a0r0, a0r1, a1r0, a1r1;
    uint4 b0h, b0l, b1h, b1l;

    auto loadA = [&](float4& x0, float4& x1, int kc) {
        x0 = *reinterpret_cast<const float4*>(Ap0 + kc);
        x1 = *reinterpret_cast<const float4*>(Ap1 + kc);
    };
    auto loadB = [&](uint4& h, uint4& l, int kc) {
        if (bact) {
            h = *reinterpret_cast<const uint4*>(Wh0 + kc);
            l = *reinterpret_cast<const uint4*>(Wl0 + kc);
        }
    };
    auto writeAB = [&](const float4& x0, const float4& x1, const uint4& h, const uint4& l) {
        ushort ha, la, hb, lb, hc, lc, hd, ld_;
        split_bf16(x0.x, ha, la);
        split_bf16(x0.y, hb, lb);
        split_bf16(x0.z, hc, lc);
        split_bf16(x0.w, hd, ld_);
        *reinterpret_cast<ushort4*>(&Ah[arow * LD + akq]) = make_ushort4(ha, hb, hc, hd);
        *reinterpret_cast<ushort4*>(&Al[arow * LD + akq]) = make_ushort4(la, lb, lc, ld_);
        split_bf16(x1.x, ha, la);
        split_bf16(x1.y, hb, lb);
        split_bf16(x1.z, hc, lc);
        split_bf16(x1.w, hd, ld_);
        *reinterpret_cast<ushort4*>(&Ah[(arow + 32) * LD + akq]) = make_ushort4(ha, hb, hc, hd);
        *reinterpret_cast<ushort4*>(&Al[(arow + 32) * LD + akq]) = make_ushort4(la, lb, lc, ld_);
        if (bact) {
            *reinterpret_cast<uint4*>(&Bh[bcol * LD + bpart]) = h;
            *reinterpret_cast<uint4*>(&Bl[bcol * LD + bpart]) = l;
        }
    };
    auto compute = [&]() {
        short8v ah, al, bhv[3], blv[3];
        ah = *reinterpret_cast<const short8v*>(&Ah[(wr + tr) * LD + quad * 8]);
        al = *reinterpret_cast<const short8v*>(&Al[(wr + tr) * LD + quad * 8]);
#pragma unroll
        for (int j = 0; j < 3; ++j) {
            bhv[j] = *reinterpret_cast<const short8v*>(&Bh[(j * 16 + tr) * LD + quad * 8]);
            blv[j] = *reinterpret_cast<const short8v*>(&Bl[(j * 16 + tr) * LD + quad * 8]);
        }
#pragma unroll
        for (int j = 0; j < 3; ++j) {
            acc[j] = __builtin_amdgcn_mfma_f32_16x16x32_bf16(ah, bhv[j], acc[j], 0, 0, 0);
            acc[j] = __builtin_amdgcn_mfma_f32_16x16x32_bf16(ah, blv[j], acc[j], 0, 0, 0);
            acc[j] = __builtin_amdgcn_mfma_f32_16x16x32_bf16(al, bhv[j], acc[j], 0, 0, 0);
        }
    };

    loadA(a0r0, a0r1, 0);
    loadB(b0h, b0l, 0);
    for (int kc = 0; kc < K; kc += 64) {
        writeAB(a0r0, a0r1, b0h, b0l);
        __syncthreads();
        loadA(a1r0, a1r1, kc + 32);
        loadB(b1h, b1l, kc + 32);
        compute();
        __syncthreads();
        writeAB(a1r0, a1r1, b1h, b1l);
        __syncthreads();
        if (kc + 64 < K) {
            loadA(a0r0, a0r1, kc + 64);
            loadB(b0h, b0l, kc + 64);
        }
        compute();
        __syncthreads();
    }

    {
        int rbase = r0 + wr + quad * 4;
        float rs[4];
#pragma unroll
        for (int reg = 0; reg < 4; ++reg) {
            int r = rbase + reg;
            rs[reg] = (r < N) ? rowscale[r] : 0.f;
        }
#pragma unroll
        for (int j = 0; j < 3; ++j) {
            int c = j * 16 + tr;
#pragma unroll
            for (int reg = 0; reg < 4; ++reg) {
                int r = rbase + reg;
                if (r < N && c < M) out[(size_t)r * M + c] = acc[j][reg] * rs[reg];
            }
        }
    }
}

// ---------------- aggregation, 128-wide bf16: 2 nodes per wave ----------------
// half-wave (32 lanes) per node, ushort4/lane: one gather inst = 512B (2 rows).
// Lanes past a node's count gather the node's own (L1-warm) row, masked add.

template <bool RELU>
__global__ __launch_bounds__(256) void agg128_bf2(const ushort* __restrict__ S,
                                                  const int* __restrict__ slots,
                                                  const int* __restrict__ cnt,
                                                  const float* __restrict__ dinv,
                                                  const float* __restrict__ bias,
                                                  float* __restrict__ out, int N) {
    int w = (blockIdx.x * blockDim.x + threadIdx.x) >> 6;
    int lane = threadIdx.x & 63;
    int npair = (N + 1) >> 1;
    if (w >= npair) return;
    int half = lane >> 5, sub = lane & 31;
    int node = 2 * w + half;
    bool valid = node < N;
    int snode = valid ? node : 0;
    const ushort4* S4 = (const ushort4*)S;  // row = 32 x ushort4
    const int* row = slots + (size_t)snode * SLOTS;
    int c = valid ? cnt[snode] : 0;
    if (c > SLOTS) c = SLOTS;
    int cmax = max(c, __shfl(c, lane ^ 32));

    ushort4 sv = S4[(size_t)snode * 32 + sub];  // self loop
    float a0 = bf2f(sv.x), a1 = bf2f(sv.y), a2 = bf2f(sv.z), a3 = bf2f(sv.w);

    int e = 0;
    for (; e + 8 <= cmax; e += 8) {
        int s[8];
#pragma unroll
        for (int u = 0; u < 8; ++u) s[u] = (e + u < c) ? row[e + u] : snode;
        ushort4 v[8];
#pragma unroll
        for (int u = 0; u < 8; ++u) v[u] = S4[(size_t)s[u] * 32 + sub];
#pragma unroll
        for (int u = 0; u < 8; ++u) {
            float m = (e + u < c) ? 1.f : 0.f;
            a0 += m * bf2f(v[u].x);
            a1 += m * bf2f(v[u].y);
            a2 += m * bf2f(v[u].z);
            a3 += m * bf2f(v[u].w);
        }
    }
    for (; e < cmax; ++e) {
        int s = (e < c) ? row[e] : snode;
        ushort4 v = S4[(size_t)s * 32 + sub];
        float m = (e < c) ? 1.f : 0.f;
        a0 += m * bf2f(v.x);
        a1 += m * bf2f(v.y);
        a2 += m * bf2f(v.z);
        a3 += m * bf2f(v.w);
    }

    if (valid) {
        float di = dinv[node];
        float4 bv = ((const float4*)bias)[sub];
        float o0 = a0 * di + bv.x;
        float o1 = a1 * di + bv.y;
        float o2 = a2 * di + bv.z;
        float o3 = a3 * di + bv.w;
        if (RELU) {
            o0 = fmaxf(o0, 0.f);
            o1 = fmaxf(o1, 0.f);
            o2 = fmaxf(o2, 0.f);
            o3 = fmaxf(o3, 0.f);
        }
        ((float4*)out)[(size_t)node * 32 + sub] = make_float4(o0, o1, o2, o3);
    }
}

// fp32 messages, M=40 (final layer), wave per node
__global__ __launch_bounds__(256) void agg40(const float* __restrict__ S,
                                             const int* __restrict__ slots,
                                             const int* __restrict__ cnt,
                                             const float* __restrict__ dinv,
                                             const float* __restrict__ bias,
                                             float* __restrict__ out, int N) {
    int wid = (blockIdx.x * blockDim.x + threadIdx.x) >> 6;
    int lane = threadIdx.x & 63;
    if (wid >= N || lane >= 40) return;
    const int* row = slots + (size_t)wid * SLOTS;
    int c = cnt[wid];
    if (c > SLOTS) c = SLOTS;
    float acc = S[(size_t)wid * 40 + lane];
    int e = 0;
    for (; e + 8 <= c; e += 8) {
        int s[8];
#pragma unroll
        for (int u = 0; u < 8; ++u) s[u] = row[e + u];
        float v[8];
#pragma unroll
        for (int u = 0; u < 8; ++u) v[u] = S[(size_t)s[u] * 40 + lane];
#pragma unroll
        for (int u = 0; u < 8; ++u) acc += v[u];
    }
    for (; e < c; ++e) acc += S[(size_t)row[e] * 40 + lane];
    out[(size_t)wid * 40 + lane] = acc * dinv[wid] + bias[lane];
}

// ---------------- launch ----------------

extern "C" void kernel_launch(void* const* d_in, const int* in_sizes, int n_in,
                              void* d_out, int out_size, void* d_ws, size_t ws_size,
                              hipStream_t stream) {
    const float* x  = (const float*)d_in[0];
    const int*   ei = (const int*)d_in[1];
    const float* W1 = (const float*)d_in[2];
    const float* b1 = (const float*)d_in[3];
    const float* W2 = (const float*)d_in[4];
    const float* b2 = (const float*)d_in[5];
    const float* W3 = (const float*)d_in[6];
    const float* b3 = (const float*)d_in[7];
    float* out = (float*)d_out;

    const int IN_DIM = 256, HID = 128;
    const int N = in_sizes[0] / IN_DIM;
    const int E = in_sizes[1] / 2;
    const int* srcE = ei;
    const int* dstE = ei + E;

    char* ws = (char*)d_ws;
    size_t off = 0;
    auto alloc = [&](size_t bytes) -> void* {
        off = (off + 255) & ~(size_t)255;
        void* p = ws + off;
        off += bytes;
        return p;
    };
    int*    cnt   = (int*)alloc((size_t)N * 4);
    float*  dinv  = (float*)alloc((size_t)N * 4);
    int*    slots = (int*)alloc((size_t)N * SLOTS * 4);     // 19.2 MB
    ushort* bufS  = (ushort*)alloc((size_t)N * HID * 4);    // bf16 msgs (128) or fp32 msgs (40)
    float*  bufH  = (float*)alloc((size_t)N * HID * 4);     // fp32 h
    ushort* W1th  = (ushort*)alloc((size_t)128 * 256 * 2);
    ushort* W1tl  = (ushort*)alloc((size_t)128 * 256 * 2);
    ushort* W2th  = (ushort*)alloc((size_t)128 * 128 * 2);
    ushort* W2tl  = (ushort*)alloc((size_t)128 * 128 * 2);
    ushort* W3th  = (ushort*)alloc((size_t)48 * 128 * 2);
    ushort* W3tl  = (ushort*)alloc((size_t)48 * 128 * 2);

    const int NB = (N + 255) / 256;
    const int AGGB = (N * WAVE + 255) / 256;
    const int AGG2B = (((N + 1) / 2) * WAVE + 255) / 256;
    const int GB64 = (N + 63) / 64;
    const int FB = FILL_NR * FILL_NCHUNK;

    // W pre-split (tiny)
    k_wsplit<<<(256 * 128 + 255) / 256, 256, 0, stream>>>(W1, W1th, W1tl, 256, 128, 128);
    k_wsplit<<<(128 * 128 + 255) / 256, 256, 0, stream>>>(W2, W2th, W2tl, 128, 128, 128);
    k_wsplit<<<(128 * 48 + 255) / 256, 256, 0, stream>>>(W3, W3th, W3tl, 128, 40, 48);

    // single-pass XCD-partitioned CSR + dinv
    hipMemsetAsync(cnt, 0, (size_t)N * 4, stream);
    k_fill_part<<<FB, 256, 0, stream>>>(srcE, dstE, cnt, slots, E, N);
    k_dinv<<<NB, 256, 0, stream>>>(cnt, dinv, N);

    // Layer 1: 256 -> 128, relu (bf16 messages)
    gemm_mfma128<256, true><<<GB64, 256, 0, stream>>>(x, W1th, W1tl, dinv, bufS, N);
    agg128_bf2<true><<<AGG2B, 256, 0, stream>>>(bufS, slots, cnt, dinv, b1, bufH, N);
    // Layer 2: 128 -> 128, relu (bf16 messages)
    gemm_mfma128<128, true><<<GB64, 256, 0, stream>>>(bufH, W2th, W2tl, dinv, bufS, N);
    agg128_bf2<true><<<AGG2B, 256, 0, stream>>>(bufS, slots, cnt, dinv, b2, bufH, N);
    // Layer 3: 128 -> 40, no relu (fp32 messages)
    gemm_mfma40<<<GB64, 256, 0, stream>>>(bufH, W3th, W3tl, dinv, (float*)bufS, N);
    agg40<<<AGGB, 256, 0, stream>>>((float*)bufS, slots, cnt, dinv, b3, out, N);
}